// Round 3
// baseline (256.662 us; speedup 1.0000x reference)
//
#include <hip/hip_runtime.h>
#include <hip/hip_bf16.h>

typedef unsigned short ushort_t;
typedef __bf16 bf16x8 __attribute__((ext_vector_type(8)));
typedef float floatx4 __attribute__((ext_vector_type(4)));

#define MFMA(a, b, c) __builtin_amdgcn_mfma_f32_16x16x32_bf16(a, b, c, 0, 0, 0)

__device__ __forceinline__ float b2f(ushort_t u) {
    union { ushort_t u; __hip_bfloat16 h; } cvt; cvt.u = u; return __bfloat162float(cvt.h);
}
__device__ __forceinline__ ushort_t f2b(float f) {
    union { ushort_t u; __hip_bfloat16 h; } cvt; cvt.h = __float2bfloat16(f); return cvt.u;
}

// async global->LDS, 16 B/lane. Dest = wave-uniform base + lane*16.
__device__ __forceinline__ void async_copy16(const ushort_t* g, ushort_t* l) {
    __builtin_amdgcn_global_load_lds(
        (const __attribute__((address_space(1))) void*)g,
        (__attribute__((address_space(3))) void*)l, 16, 0, 0);
}

// ---------------------------------------------------------------------------
// Merged preprocessing: one launch, three block-ranges.
//   [0, 4096)        : x fp32 -> bf16 (8 elems/thread)
//   [4096, 7168)     : W_qkv transpose+cvt with QKV column permutation
//   [7168, 8192)     : W_o transpose+cvt
// ---------------------------------------------------------------------------
__global__ void prep(const float* __restrict__ xin, ushort_t* __restrict__ xb,
                     const float* __restrict__ Wqkv, ushort_t* __restrict__ WqkvT,
                     const float* __restrict__ Wo, ushort_t* __restrict__ WoT) {
    __shared__ float tile[32][33];
    int bb = blockIdx.x;
    if (bb < 4096) {
        int i = bb * 256 + threadIdx.x;
        const float4* xf = (const float4*)xin;
        float4 a = xf[i * 2], b = xf[i * 2 + 1];
        union { ushort_t s[8]; uint4 v; } p;
        p.s[0] = f2b(a.x); p.s[1] = f2b(a.y); p.s[2] = f2b(a.z); p.s[3] = f2b(a.w);
        p.s[4] = f2b(b.x); p.s[5] = f2b(b.y); p.s[6] = f2b(b.z); p.s[7] = f2b(b.w);
        ((uint4*)xb)[i] = p.v;
    } else if (bb < 7168) {
        int b2 = bb - 4096;
        int p0 = (b2 % 96) * 32, k0 = (b2 / 96) * 32;
        int which = p0 >> 10, rem = p0 & 1023;
        int n0 = (rem >> 6) * 192 + which * 64 + (rem & 63);
        int tx = threadIdx.x & 31, ty = threadIdx.x >> 5;
#pragma unroll
        for (int i = 0; i < 4; ++i)
            tile[ty + i * 8][tx] = Wqkv[(size_t)(k0 + ty + i * 8) * 3072 + n0 + tx];
        __syncthreads();
#pragma unroll
        for (int i = 0; i < 4; ++i)
            WqkvT[(size_t)(p0 + ty + i * 8) * 1024 + k0 + tx] = f2b(tile[tx][ty + i * 8]);
    } else {
        int b3 = bb - 7168;
        int n0 = (b3 & 31) * 32, k0 = (b3 >> 5) * 32;
        int tx = threadIdx.x & 31, ty = threadIdx.x >> 5;
#pragma unroll
        for (int i = 0; i < 4; ++i)
            tile[ty + i * 8][tx] = Wo[(size_t)(k0 + ty + i * 8) * 1024 + n0 + tx];
        __syncthreads();
#pragma unroll
        for (int i = 0; i < 4; ++i)
            WoT[(size_t)(n0 + ty + i * 8) * 1024 + k0 + tx] = f2b(tile[tx][ty + i * 8]);
    }
}

// swizzled index into the 128x128 transpose buffer
__device__ __forceinline__ int tswz(int n, int m) {
    return n * 128 + (((m >> 3) ^ (n & 15)) << 3) + (m & 7);
}

// ---------------------------------------------------------------------------
// GEMM1: qkv = x @ Wqkv_perm + b.  Q is PRE-SCALED by 0.125*log2(e).
// XCD-chunked block swizzle: 1536 blocks = 8 XCD x 192; each XCD owns 3
// B-panels (256 KB each, L2-resident) and streams A.  4 blocks/CU.
// ---------------------------------------------------------------------------
__global__ __launch_bounds__(256, 4) void gemm_qkv(
    const ushort_t* __restrict__ A,
    const ushort_t* __restrict__ Bt,
    const float* __restrict__ bias,
    ushort_t* __restrict__ Qb, ushort_t* __restrict__ Kb, ushort_t* __restrict__ Vtb) {
    const int K = 1024;
    __shared__ __align__(16) ushort_t SH[16384];
    ushort_t* Alds = SH;
    ushort_t* Blds = SH + 8192;
    int tid = threadIdx.x;
    int wave = tid >> 6, lane = tid & 63;
    int quad = lane >> 4, l16 = lane & 15;
    int wm = (wave >> 1) * 64, wn = (wave & 1) * 64;

    // XCD-aware remap (bijective: 1536 = 8*192)
    int lin = blockIdx.x + 64 * blockIdx.y;
    int nl = (lin & 7) * 192 + (lin >> 3);
    int m0 = (nl & 63) * 128, n0 = (nl >> 6) * 128;

    floatx4 acc[4][4] = {};

    int srow[4], scol[4];
#pragma unroll
    for (int p = 0; p < 4; ++p) {
        int slot = (wave * 4 + p) * 64 + lane;
        int row = slot >> 3;
        srow[p] = row;
        scol[p] = ((slot & 7) ^ (row & 7)) * 8;
    }

    for (int kt = 0; kt < 16; ++kt) {
        int k0 = kt * 64;
        __syncthreads();
#pragma unroll
        for (int p = 0; p < 4; ++p) {
            int t = wave * 4 + p;
            async_copy16(&A[(m0 + srow[p]) * K + k0 + scol[p]], &Alds[t * 512]);
            async_copy16(&Bt[(n0 + srow[p]) * K + k0 + scol[p]], &Blds[t * 512]);
        }
        __syncthreads();
#pragma unroll
        for (int ki = 0; ki < 2; ++ki) {
            bf16x8 af[4], bfv[4];
            int sc = ((ki * 4 + quad) ^ (l16 & 7)) * 8;
#pragma unroll
            for (int i = 0; i < 4; ++i) {
                __builtin_memcpy(&af[i],  &Alds[(wm + i * 16 + l16) * 64 + sc], 16);
                __builtin_memcpy(&bfv[i], &Blds[(wn + i * 16 + l16) * 64 + sc], 16);
            }
#pragma unroll
            for (int i = 0; i < 4; ++i)
#pragma unroll
                for (int j = 0; j < 4; ++j)
                    acc[i][j] = MFMA(af[i], bfv[j], acc[i][j]);
        }
    }

    int which = n0 >> 10;              // 0=Q, 1=K, 2=V
    int b = m0 >> 10;

    if (which < 2) {
        ushort_t* dst = which ? Kb : Qb;
        float sc = which ? 1.0f : 0.18033688f;   // Q pre-scale: 0.125*log2(e)
#pragma unroll
        for (int j = 0; j < 4; ++j) {
            int C = n0 + wn + j * 16 + l16;
            int c = C & 1023;
            int h = c >> 6, d = c & 63;
            float bv = bias[((C >> 6) & 15) * 192 + which * 64 + (C & 63)];
            size_t hb = (size_t)(b * 16 + h) * 65536 + d;
#pragma unroll
            for (int i = 0; i < 4; ++i)
#pragma unroll
                for (int g = 0; g < 4; ++g) {
                    int n_tok = (m0 & 1023) + wm + i * 16 + quad * 4 + g;
                    dst[hb + (size_t)n_tok * 64] = f2b((acc[i][j][g] + bv) * sc);
                }
        }
    } else {
        __syncthreads();
#pragma unroll
        for (int j = 0; j < 4; ++j) {
            int C = n0 + wn + j * 16 + l16;
            int nl2 = wn + j * 16 + l16;
            float bv = bias[((C >> 6) & 15) * 192 + 128 + (C & 63)];
#pragma unroll
            for (int i = 0; i < 4; ++i)
#pragma unroll
                for (int g = 0; g < 4; ++g) {
                    int ml = wm + i * 16 + quad * 4 + g;
                    SH[tswz(nl2, ml)] = f2b(acc[i][j][g] + bv);
                }
        }
        __syncthreads();
        int r = tid >> 1, half = tid & 1;
        int vcol = (n0 - 2048) + r;
        int h = vcol >> 6, d = vcol & 63;
        size_t base = ((size_t)(b * 16 + h) * 64 + d) * 1024 + (m0 & 1023) + half * 64;
#pragma unroll
        for (int i8 = 0; i8 < 8; ++i8) {
            int chunk = half * 8 + i8;
            uint4 v;
            __builtin_memcpy(&v, &SH[r * 128 + ((chunk ^ (r & 15)) << 3)], 16);
            __builtin_memcpy(&Vtb[base + i8 * 8], &v, 16);
        }
    }
}

// ---------------------------------------------------------------------------
// Flash attention v7: one 128-row q-tile per block, SINGLE-buffered K/V
// (two barriers per K-tile, gemm-style) -> LDS 35840 B -> 4 blocks/CU
// (16 waves/CU; grid 1024 = exactly 4/CU, zero tail).  Inter-block overlap
// covers the staging drain.  XCD remap keeps each XCD's K/V working set at
// 16 heads x 256 KB = 4 MB = its L2.  Q pre-scaled -> P = exp2(S) directly.
// ---------------------------------------------------------------------------
__global__ __launch_bounds__(256, 4) void attn(
    const ushort_t* __restrict__ Qb, const ushort_t* __restrict__ Kb,
    const ushort_t* __restrict__ Vtb, ushort_t* __restrict__ heads) {
    __shared__ __align__(16) ushort_t Klds[4096];       // swizzled, row = key
    __shared__ __align__(16) ushort_t Vlds[4096];       // swizzled, row = d
    __shared__ __align__(16) ushort_t Plds[128 * 76];   // [q-row][key]
    int tid = threadIdx.x;
    int wave = tid >> 6, lane = tid & 63;
    int quad = lane >> 4, l16 = lane & 15;

    // XCD-aware remap: slot within this XCD iterates q-tiles fastest.
    int slot = blockIdx.y + 16 * blockIdx.z;        // [0,128) per XCD
    int bh = blockIdx.x + 8 * (slot >> 3);          // [0,128), bh%8 == XCD
    int qx = slot & 7;                              // q-tile index [0,8)
    int b = bh >> 4, h = bh & 15;
    const ushort_t* Qh = Qb + (size_t)bh * 65536;
    const ushort_t* Kh = Kb + (size_t)bh * 65536;
    const ushort_t* Vh = Vtb + (size_t)bh * 65536;

    bf16x8 qa[2][2];                   // [mi][ki], B-fragment role
#pragma unroll
    for (int mi = 0; mi < 2; ++mi) {
        int qrow = qx * 128 + wave * 32 + mi * 16 + l16;
        __builtin_memcpy(&qa[mi][0], &Qh[qrow * 64 + quad * 8], 16);
        __builtin_memcpy(&qa[mi][1], &Qh[qrow * 64 + 32 + quad * 8], 16);
    }

    floatx4 oacc[2][4] = {};
    floatx4 oext[2] = {};

    bf16x8 onesfrag;
    {
        ushort_t v = (l16 == 0) ? (ushort_t)0x3F80 : (ushort_t)0;
        ushort_t tmp[8] = {v, v, v, v, v, v, v, v};
        __builtin_memcpy(&onesfrag, tmp, 16);
    }

    int srow[2], scol[2];
#pragma unroll
    for (int p = 0; p < 2; ++p) {
        int slot2 = (wave * 2 + p) * 64 + lane;
        int row = slot2 >> 3;
        srow[p] = row;
        scol[p] = ((slot2 & 7) ^ (row & 7)) * 8;
    }

    for (int kt = 0; kt < 16; ++kt) {
        int k0 = kt * 64;
        __syncthreads();   // all waves done reading prev tile
#pragma unroll
        for (int p = 0; p < 2; ++p) {
            int t = wave * 2 + p;
            async_copy16(&Kh[(k0 + srow[p]) * 64 + scol[p]], &Klds[t * 512]);
            async_copy16(&Vh[srow[p] * 1024 + k0 + scol[p]], &Vlds[t * 512]);
        }
        __syncthreads();   // staged data visible (vmcnt drained by compiler)

        // ---- St = K Q^T; P = exp2(St) -> Plds
        bf16x8 kf[4][2];
#pragma unroll
        for (int n = 0; n < 4; ++n)
#pragma unroll
            for (int ki = 0; ki < 2; ++ki) {
                int sc = ((ki * 4 + quad) ^ (l16 & 7)) * 8;
                __builtin_memcpy(&kf[n][ki], &Klds[(n * 16 + l16) * 64 + sc], 16);
            }
#pragma unroll
        for (int mi = 0; mi < 2; ++mi)
#pragma unroll
            for (int n = 0; n < 4; ++n) {
                floatx4 z = {0.f, 0.f, 0.f, 0.f};
#pragma unroll
                for (int ki = 0; ki < 2; ++ki)
                    z = MFMA(kf[n][ki], qa[mi][ki], z);
                union { ushort_t s[4]; double d8; } pk;
#pragma unroll
                for (int g = 0; g < 4; ++g)
                    pk.s[g] = f2b(__builtin_exp2f(z[g]));
                __builtin_memcpy(
                    &Plds[(wave * 32 + mi * 16 + l16) * 76 + n * 16 + quad * 4],
                    &pk, 8);
            }

        // ---- O += P V ; l += P ones  (P read back same-wave, no barrier)
        bf16x8 vf[4][2];
#pragma unroll
        for (int n = 0; n < 4; ++n)
#pragma unroll
            for (int ki = 0; ki < 2; ++ki) {
                int sc = ((ki * 4 + quad) ^ (l16 & 7)) * 8;
                __builtin_memcpy(&vf[n][ki], &Vlds[(n * 16 + l16) * 64 + sc], 16);
            }
#pragma unroll
        for (int mi = 0; mi < 2; ++mi) {
            bf16x8 pa[2];
            int prow = wave * 32 + mi * 16 + l16;
#pragma unroll
            for (int ki = 0; ki < 2; ++ki)
                __builtin_memcpy(&pa[ki], &Plds[prow * 76 + ki * 32 + quad * 8], 16);
            __builtin_amdgcn_s_setprio(1);
#pragma unroll
            for (int n = 0; n < 4; ++n)
#pragma unroll
                for (int ki = 0; ki < 2; ++ki)
                    oacc[mi][n] = MFMA(pa[ki], vf[n][ki], oacc[mi][n]);
#pragma unroll
            for (int ki = 0; ki < 2; ++ki)
                oext[mi] = MFMA(pa[ki], onesfrag, oext[mi]);
            __builtin_amdgcn_s_setprio(0);
        }
    }

    // normalize + write heads (B, N, H*HD) bf16
#pragma unroll
    for (int mi = 0; mi < 2; ++mi)
#pragma unroll
        for (int g = 0; g < 4; ++g) {
            float l = __shfl(oext[mi][g], (lane & 48));
            float inv = 1.f / l;
            int n_tok = qx * 128 + wave * 32 + mi * 16 + quad * 4 + g;
#pragma unroll
            for (int n = 0; n < 4; ++n)
                heads[(size_t)(b * 1024 + n_tok) * 1024 + h * 64 + n * 16 + l16] =
                    f2b(oacc[mi][n][g] * inv);
        }
}

// ---------------------------------------------------------------------------
// GEMM2: out = heads(8192x1024) @ W_o + b_o  -> FP32 d_out
// XCD-chunked swizzle: 512 blocks = 8 XCD x 64; each XCD owns exactly one
// 128-col B-panel (256 KB, L2-resident) and streams A.
// ---------------------------------------------------------------------------
__global__ __launch_bounds__(256, 4) void gemm_out(
    const ushort_t* __restrict__ A,
    const ushort_t* __restrict__ Bt,
    const float* __restrict__ bias,
    float* __restrict__ out) {
    const int K = 1024;
    __shared__ __align__(16) ushort_t Alds[128 * 64];
    __shared__ __align__(16) ushort_t Blds[128 * 64];
    int tid = threadIdx.x;
    int wave = tid >> 6, lane = tid & 63;
    int quad = lane >> 4, l16 = lane & 15;
    int wm = (wave >> 1) * 64, wn = (wave & 1) * 64;

    // XCD-aware remap (bijective: 512 = 8*64)
    int lin = blockIdx.x + 64 * blockIdx.y;
    int nl = (lin & 7) * 64 + (lin >> 3);
    int m0 = (nl & 63) * 128, n0 = (nl >> 6) * 128;

    floatx4 acc[4][4] = {};

    int srow[4], scol[4];
#pragma unroll
    for (int p = 0; p < 4; ++p) {
        int slot = (wave * 4 + p) * 64 + lane;
        int row = slot >> 3;
        srow[p] = row;
        scol[p] = ((slot & 7) ^ (row & 7)) * 8;
    }

    for (int kt = 0; kt < 16; ++kt) {
        int k0 = kt * 64;
        __syncthreads();
#pragma unroll
        for (int p = 0; p < 4; ++p) {
            int t = wave * 4 + p;
            async_copy16(&A[(m0 + srow[p]) * K + k0 + scol[p]], &Alds[t * 512]);
            async_copy16(&Bt[(n0 + srow[p]) * K + k0 + scol[p]], &Blds[t * 512]);
        }
        __syncthreads();
#pragma unroll
        for (int ki = 0; ki < 2; ++ki) {
            bf16x8 af[4], bfv[4];
            int sc = ((ki * 4 + quad) ^ (l16 & 7)) * 8;
#pragma unroll
            for (int i = 0; i < 4; ++i) {
                __builtin_memcpy(&af[i],  &Alds[(wm + i * 16 + l16) * 64 + sc], 16);
                __builtin_memcpy(&bfv[i], &Blds[(wn + i * 16 + l16) * 64 + sc], 16);
            }
#pragma unroll
            for (int i = 0; i < 4; ++i)
#pragma unroll
                for (int j = 0; j < 4; ++j)
                    acc[i][j] = MFMA(af[i], bfv[j], acc[i][j]);
        }
    }

#pragma unroll
    for (int j = 0; j < 4; ++j) {
        int C = n0 + wn + j * 16 + l16;
        float bv = bias[C];
#pragma unroll
        for (int i = 0; i < 4; ++i)
#pragma unroll
            for (int g = 0; g < 4; ++g) {
                int R = m0 + wm + i * 16 + quad * 4 + g;
                out[(size_t)R * 1024 + C] = acc[i][j][g] + bv;
            }
    }
}

// ---------------------------------------------------------------------------
extern "C" void kernel_launch(void* const* d_in, const int* in_sizes, int n_in,
                              void* d_out, int out_size, void* d_ws, size_t ws_size,
                              hipStream_t stream) {
    const float* x    = (const float*)d_in[0];
    const float* Wqkv = (const float*)d_in[1];
    const float* bqkv = (const float*)d_in[2];
    const float* Wo   = (const float*)d_in[3];
    const float* bo   = (const float*)d_in[4];

    char* ws = (char*)d_ws;
    const size_t MB = 1u << 20;
    // Layout (peak 72 MB):
    //   xb    0-16   (dead after gemm_qkv; heads aliases it)
    //   Qb   16-32, Kb 32-48, Vtb 48-64
    //   WqkvT 64-70 (dead after gemm_qkv)
    //   WoT  70-72  (live until gemm_out)
    ushort_t* xb    = (ushort_t*)(ws);
    ushort_t* Qb    = (ushort_t*)(ws + 16 * MB);
    ushort_t* Kb    = (ushort_t*)(ws + 32 * MB);
    ushort_t* Vtb   = (ushort_t*)(ws + 48 * MB);
    ushort_t* WqkvT = (ushort_t*)(ws + 64 * MB);
    ushort_t* WoT   = (ushort_t*)(ws + 70 * MB);
    ushort_t* heads = (ushort_t*)(ws);             // alias xb

    prep<<<8192, 256, 0, stream>>>(x, xb, Wqkv, WqkvT, Wo, WoT);
    gemm_qkv<<<dim3(64, 24), 256, 0, stream>>>(xb, WqkvT, bqkv, Qb, Kb, Vtb);
    attn<<<dim3(8, 16, 8), 256, 0, stream>>>(Qb, Kb, Vtb, heads);
    gemm_out<<<dim3(64, 8), 256, 0, stream>>>(heads, WoT, bo, (float*)d_out);
}

// Round 4
// 232.891 us; speedup vs baseline: 1.1021x; 1.1021x over previous
//
#include <hip/hip_runtime.h>
#include <hip/hip_bf16.h>

typedef unsigned short ushort_t;
typedef __bf16 bf16x8 __attribute__((ext_vector_type(8)));
typedef float floatx4 __attribute__((ext_vector_type(4)));

#define MFMA(a, b, c) __builtin_amdgcn_mfma_f32_16x16x32_bf16(a, b, c, 0, 0, 0)

__device__ __forceinline__ float b2f(ushort_t u) {
    union { ushort_t u; __hip_bfloat16 h; } cvt; cvt.u = u; return __bfloat162float(cvt.h);
}
__device__ __forceinline__ ushort_t f2b(float f) {
    union { ushort_t u; __hip_bfloat16 h; } cvt; cvt.h = __float2bfloat16(f); return cvt.u;
}

// async global->LDS, 16 B/lane. Dest = wave-uniform base + lane*16.
__device__ __forceinline__ void async_copy16(const ushort_t* g, ushort_t* l) {
    __builtin_amdgcn_global_load_lds(
        (const __attribute__((address_space(1))) void*)g,
        (__attribute__((address_space(3))) void*)l, 16, 0, 0);
}

// ---------------------------------------------------------------------------
// Merged preprocessing: one launch, three block-ranges.
//   [0, 4096)        : x fp32 -> bf16 (8 elems/thread)
//   [4096, 7168)     : W_qkv transpose+cvt with QKV column permutation
//   [7168, 8192)     : W_o transpose+cvt
// ---------------------------------------------------------------------------
__global__ void prep(const float* __restrict__ xin, ushort_t* __restrict__ xb,
                     const float* __restrict__ Wqkv, ushort_t* __restrict__ WqkvT,
                     const float* __restrict__ Wo, ushort_t* __restrict__ WoT) {
    __shared__ float tile[32][33];
    int bb = blockIdx.x;
    if (bb < 4096) {
        int i = bb * 256 + threadIdx.x;
        const float4* xf = (const float4*)xin;
        float4 a = xf[i * 2], b = xf[i * 2 + 1];
        union { ushort_t s[8]; uint4 v; } p;
        p.s[0] = f2b(a.x); p.s[1] = f2b(a.y); p.s[2] = f2b(a.z); p.s[3] = f2b(a.w);
        p.s[4] = f2b(b.x); p.s[5] = f2b(b.y); p.s[6] = f2b(b.z); p.s[7] = f2b(b.w);
        ((uint4*)xb)[i] = p.v;
    } else if (bb < 7168) {
        int b2 = bb - 4096;
        int p0 = (b2 % 96) * 32, k0 = (b2 / 96) * 32;
        int which = p0 >> 10, rem = p0 & 1023;
        int n0 = (rem >> 6) * 192 + which * 64 + (rem & 63);
        int tx = threadIdx.x & 31, ty = threadIdx.x >> 5;
#pragma unroll
        for (int i = 0; i < 4; ++i)
            tile[ty + i * 8][tx] = Wqkv[(size_t)(k0 + ty + i * 8) * 3072 + n0 + tx];
        __syncthreads();
#pragma unroll
        for (int i = 0; i < 4; ++i)
            WqkvT[(size_t)(p0 + ty + i * 8) * 1024 + k0 + tx] = f2b(tile[tx][ty + i * 8]);
    } else {
        int b3 = bb - 7168;
        int n0 = (b3 & 31) * 32, k0 = (b3 >> 5) * 32;
        int tx = threadIdx.x & 31, ty = threadIdx.x >> 5;
#pragma unroll
        for (int i = 0; i < 4; ++i)
            tile[ty + i * 8][tx] = Wo[(size_t)(k0 + ty + i * 8) * 1024 + n0 + tx];
        __syncthreads();
#pragma unroll
        for (int i = 0; i < 4; ++i)
            WoT[(size_t)(n0 + ty + i * 8) * 1024 + k0 + tx] = f2b(tile[tx][ty + i * 8]);
    }
}

// swizzled index into the 128x128 transpose buffer
__device__ __forceinline__ int tswz(int n, int m) {
    return n * 128 + (((m >> 3) ^ (n & 15)) << 3) + (m & 7);
}

// ---------------------------------------------------------------------------
// GEMM1: qkv = x @ Wqkv_perm + b.  Q is PRE-SCALED by 0.125*log2(e).
// NATURAL block order (m fastest): all XCDs share one B-panel at a time
// (L2-replicated, 256 KB), A working set per time-slice = 2 MB/XCD, A
// re-reads across n-panels absorbed by L3.  (XCD-chunked swizzle measured
// WORSE: each XCD streamed full 16 MB A per panel, FETCH 44->181 MB.)
// ---------------------------------------------------------------------------
__global__ __launch_bounds__(256, 4) void gemm_qkv(
    const ushort_t* __restrict__ A,
    const ushort_t* __restrict__ Bt,
    const float* __restrict__ bias,
    ushort_t* __restrict__ Qb, ushort_t* __restrict__ Kb, ushort_t* __restrict__ Vtb) {
    const int K = 1024;
    __shared__ __align__(16) ushort_t SH[16384];
    ushort_t* Alds = SH;
    ushort_t* Blds = SH + 8192;
    int tid = threadIdx.x;
    int wave = tid >> 6, lane = tid & 63;
    int quad = lane >> 4, l16 = lane & 15;
    int wm = (wave >> 1) * 64, wn = (wave & 1) * 64;
    int m0 = blockIdx.x * 128, n0 = blockIdx.y * 128;

    floatx4 acc[4][4] = {};

    int srow[4], scol[4];
#pragma unroll
    for (int p = 0; p < 4; ++p) {
        int slot = (wave * 4 + p) * 64 + lane;
        int row = slot >> 3;
        srow[p] = row;
        scol[p] = ((slot & 7) ^ (row & 7)) * 8;
    }

    for (int kt = 0; kt < 16; ++kt) {
        int k0 = kt * 64;
        __syncthreads();
#pragma unroll
        for (int p = 0; p < 4; ++p) {
            int t = wave * 4 + p;
            async_copy16(&A[(m0 + srow[p]) * K + k0 + scol[p]], &Alds[t * 512]);
            async_copy16(&Bt[(n0 + srow[p]) * K + k0 + scol[p]], &Blds[t * 512]);
        }
        __syncthreads();
#pragma unroll
        for (int ki = 0; ki < 2; ++ki) {
            bf16x8 af[4], bfv[4];
            int sc = ((ki * 4 + quad) ^ (l16 & 7)) * 8;
#pragma unroll
            for (int i = 0; i < 4; ++i) {
                __builtin_memcpy(&af[i],  &Alds[(wm + i * 16 + l16) * 64 + sc], 16);
                __builtin_memcpy(&bfv[i], &Blds[(wn + i * 16 + l16) * 64 + sc], 16);
            }
#pragma unroll
            for (int i = 0; i < 4; ++i)
#pragma unroll
                for (int j = 0; j < 4; ++j)
                    acc[i][j] = MFMA(af[i], bfv[j], acc[i][j]);
        }
    }

    int which = n0 >> 10;              // 0=Q, 1=K, 2=V
    int b = m0 >> 10;

    if (which < 2) {
        ushort_t* dst = which ? Kb : Qb;
        float sc = which ? 1.0f : 0.18033688f;   // Q pre-scale: 0.125*log2(e)
#pragma unroll
        for (int j = 0; j < 4; ++j) {
            int C = n0 + wn + j * 16 + l16;
            int c = C & 1023;
            int h = c >> 6, d = c & 63;
            float bv = bias[((C >> 6) & 15) * 192 + which * 64 + (C & 63)];
            size_t hb = (size_t)(b * 16 + h) * 65536 + d;
#pragma unroll
            for (int i = 0; i < 4; ++i)
#pragma unroll
                for (int g = 0; g < 4; ++g) {
                    int n_tok = (m0 & 1023) + wm + i * 16 + quad * 4 + g;
                    dst[hb + (size_t)n_tok * 64] = f2b((acc[i][j][g] + bv) * sc);
                }
        }
    } else {
        __syncthreads();
#pragma unroll
        for (int j = 0; j < 4; ++j) {
            int C = n0 + wn + j * 16 + l16;
            int nl2 = wn + j * 16 + l16;
            float bv = bias[((C >> 6) & 15) * 192 + 128 + (C & 63)];
#pragma unroll
            for (int i = 0; i < 4; ++i)
#pragma unroll
                for (int g = 0; g < 4; ++g) {
                    int ml = wm + i * 16 + quad * 4 + g;
                    SH[tswz(nl2, ml)] = f2b(acc[i][j][g] + bv);
                }
        }
        __syncthreads();
        int r = tid >> 1, half = tid & 1;
        int vcol = (n0 - 2048) + r;
        int h = vcol >> 6, d = vcol & 63;
        size_t base = ((size_t)(b * 16 + h) * 64 + d) * 1024 + (m0 & 1023) + half * 64;
#pragma unroll
        for (int i8 = 0; i8 < 8; ++i8) {
            int chunk = half * 8 + i8;
            uint4 v;
            __builtin_memcpy(&v, &SH[r * 128 + ((chunk ^ (r & 15)) << 3)], 16);
            __builtin_memcpy(&Vtb[base + i8 * 8], &v, 16);
        }
    }
}

// ---------------------------------------------------------------------------
// Flash attention v7: one 128-row q-tile per block, SINGLE-buffered K/V
// (two barriers per K-tile, gemm-style) -> LDS 35840 B -> 4 blocks/CU
// (16 waves/CU; grid 1024 = exactly 4/CU, zero tail).  Inter-block overlap
// covers the staging drain.  XCD remap keeps each XCD's K/V working set at
// 16 heads x 256 KB = 4 MB = its L2.  Q pre-scaled -> P = exp2(S) directly.
// ---------------------------------------------------------------------------
__global__ __launch_bounds__(256, 4) void attn(
    const ushort_t* __restrict__ Qb, const ushort_t* __restrict__ Kb,
    const ushort_t* __restrict__ Vtb, ushort_t* __restrict__ heads) {
    __shared__ __align__(16) ushort_t Klds[4096];       // swizzled, row = key
    __shared__ __align__(16) ushort_t Vlds[4096];       // swizzled, row = d
    __shared__ __align__(16) ushort_t Plds[128 * 76];   // [q-row][key]
    int tid = threadIdx.x;
    int wave = tid >> 6, lane = tid & 63;
    int quad = lane >> 4, l16 = lane & 15;

    // XCD-aware remap: slot within this XCD iterates q-tiles fastest.
    int slot = blockIdx.y + 16 * blockIdx.z;        // [0,128) per XCD
    int bh = blockIdx.x + 8 * (slot >> 3);          // [0,128), bh%8 == XCD
    int qx = slot & 7;                              // q-tile index [0,8)
    int b = bh >> 4, h = bh & 15;
    const ushort_t* Qh = Qb + (size_t)bh * 65536;
    const ushort_t* Kh = Kb + (size_t)bh * 65536;
    const ushort_t* Vh = Vtb + (size_t)bh * 65536;

    bf16x8 qa[2][2];                   // [mi][ki], B-fragment role
#pragma unroll
    for (int mi = 0; mi < 2; ++mi) {
        int qrow = qx * 128 + wave * 32 + mi * 16 + l16;
        __builtin_memcpy(&qa[mi][0], &Qh[qrow * 64 + quad * 8], 16);
        __builtin_memcpy(&qa[mi][1], &Qh[qrow * 64 + 32 + quad * 8], 16);
    }

    floatx4 oacc[2][4] = {};
    floatx4 oext[2] = {};

    bf16x8 onesfrag;
    {
        ushort_t v = (l16 == 0) ? (ushort_t)0x3F80 : (ushort_t)0;
        ushort_t tmp[8] = {v, v, v, v, v, v, v, v};
        __builtin_memcpy(&onesfrag, tmp, 16);
    }

    int srow[2], scol[2];
#pragma unroll
    for (int p = 0; p < 2; ++p) {
        int slot2 = (wave * 2 + p) * 64 + lane;
        int row = slot2 >> 3;
        srow[p] = row;
        scol[p] = ((slot2 & 7) ^ (row & 7)) * 8;
    }

    for (int kt = 0; kt < 16; ++kt) {
        int k0 = kt * 64;
        __syncthreads();   // all waves done reading prev tile
#pragma unroll
        for (int p = 0; p < 2; ++p) {
            int t = wave * 2 + p;
            async_copy16(&Kh[(k0 + srow[p]) * 64 + scol[p]], &Klds[t * 512]);
            async_copy16(&Vh[srow[p] * 1024 + k0 + scol[p]], &Vlds[t * 512]);
        }
        __syncthreads();   // staged data visible (vmcnt drained by compiler)

        // ---- St = K Q^T; P = exp2(St) -> Plds
        bf16x8 kf[4][2];
#pragma unroll
        for (int n = 0; n < 4; ++n)
#pragma unroll
            for (int ki = 0; ki < 2; ++ki) {
                int sc = ((ki * 4 + quad) ^ (l16 & 7)) * 8;
                __builtin_memcpy(&kf[n][ki], &Klds[(n * 16 + l16) * 64 + sc], 16);
            }
#pragma unroll
        for (int mi = 0; mi < 2; ++mi)
#pragma unroll
            for (int n = 0; n < 4; ++n) {
                floatx4 z = {0.f, 0.f, 0.f, 0.f};
#pragma unroll
                for (int ki = 0; ki < 2; ++ki)
                    z = MFMA(kf[n][ki], qa[mi][ki], z);
                union { ushort_t s[4]; double d8; } pk;
#pragma unroll
                for (int g = 0; g < 4; ++g)
                    pk.s[g] = f2b(__builtin_exp2f(z[g]));
                __builtin_memcpy(
                    &Plds[(wave * 32 + mi * 16 + l16) * 76 + n * 16 + quad * 4],
                    &pk, 8);
            }

        // ---- O += P V ; l += P ones  (P read back same-wave, no barrier)
        bf16x8 vf[4][2];
#pragma unroll
        for (int n = 0; n < 4; ++n)
#pragma unroll
            for (int ki = 0; ki < 2; ++ki) {
                int sc = ((ki * 4 + quad) ^ (l16 & 7)) * 8;
                __builtin_memcpy(&vf[n][ki], &Vlds[(n * 16 + l16) * 64 + sc], 16);
            }
#pragma unroll
        for (int mi = 0; mi < 2; ++mi) {
            bf16x8 pa[2];
            int prow = wave * 32 + mi * 16 + l16;
#pragma unroll
            for (int ki = 0; ki < 2; ++ki)
                __builtin_memcpy(&pa[ki], &Plds[prow * 76 + ki * 32 + quad * 8], 16);
            __builtin_amdgcn_s_setprio(1);
#pragma unroll
            for (int n = 0; n < 4; ++n)
#pragma unroll
                for (int ki = 0; ki < 2; ++ki)
                    oacc[mi][n] = MFMA(pa[ki], vf[n][ki], oacc[mi][n]);
#pragma unroll
            for (int ki = 0; ki < 2; ++ki)
                oext[mi] = MFMA(pa[ki], onesfrag, oext[mi]);
            __builtin_amdgcn_s_setprio(0);
        }
    }

    // normalize + write heads (B, N, H*HD) bf16
#pragma unroll
    for (int mi = 0; mi < 2; ++mi)
#pragma unroll
        for (int g = 0; g < 4; ++g) {
            float l = __shfl(oext[mi][g], (lane & 48));
            float inv = 1.f / l;
            int n_tok = qx * 128 + wave * 32 + mi * 16 + quad * 4 + g;
#pragma unroll
            for (int n = 0; n < 4; ++n)
                heads[(size_t)(b * 1024 + n_tok) * 1024 + h * 64 + n * 16 + l16] =
                    f2b(oacc[mi][n][g] * inv);
        }
}

// ---------------------------------------------------------------------------
// GEMM2: out = heads(8192x1024) @ W_o + b_o  -> FP32 d_out.  Natural order.
// ---------------------------------------------------------------------------
__global__ __launch_bounds__(256, 4) void gemm_out(
    const ushort_t* __restrict__ A,
    const ushort_t* __restrict__ Bt,
    const float* __restrict__ bias,
    float* __restrict__ out) {
    const int K = 1024;
    __shared__ __align__(16) ushort_t Alds[128 * 64];
    __shared__ __align__(16) ushort_t Blds[128 * 64];
    int tid = threadIdx.x;
    int wave = tid >> 6, lane = tid & 63;
    int quad = lane >> 4, l16 = lane & 15;
    int wm = (wave >> 1) * 64, wn = (wave & 1) * 64;
    int m0 = blockIdx.x * 128, n0 = blockIdx.y * 128;

    floatx4 acc[4][4] = {};

    int srow[4], scol[4];
#pragma unroll
    for (int p = 0; p < 4; ++p) {
        int slot = (wave * 4 + p) * 64 + lane;
        int row = slot >> 3;
        srow[p] = row;
        scol[p] = ((slot & 7) ^ (row & 7)) * 8;
    }

    for (int kt = 0; kt < 16; ++kt) {
        int k0 = kt * 64;
        __syncthreads();
#pragma unroll
        for (int p = 0; p < 4; ++p) {
            int t = wave * 4 + p;
            async_copy16(&A[(m0 + srow[p]) * K + k0 + scol[p]], &Alds[t * 512]);
            async_copy16(&Bt[(n0 + srow[p]) * K + k0 + scol[p]], &Blds[t * 512]);
        }
        __syncthreads();
#pragma unroll
        for (int ki = 0; ki < 2; ++ki) {
            bf16x8 af[4], bfv[4];
            int sc = ((ki * 4 + quad) ^ (l16 & 7)) * 8;
#pragma unroll
            for (int i = 0; i < 4; ++i) {
                __builtin_memcpy(&af[i],  &Alds[(wm + i * 16 + l16) * 64 + sc], 16);
                __builtin_memcpy(&bfv[i], &Blds[(wn + i * 16 + l16) * 64 + sc], 16);
            }
#pragma unroll
            for (int i = 0; i < 4; ++i)
#pragma unroll
                for (int j = 0; j < 4; ++j)
                    acc[i][j] = MFMA(af[i], bfv[j], acc[i][j]);
        }
    }

#pragma unroll
    for (int j = 0; j < 4; ++j) {
        int C = n0 + wn + j * 16 + l16;
        float bv = bias[C];
#pragma unroll
        for (int i = 0; i < 4; ++i)
#pragma unroll
            for (int g = 0; g < 4; ++g) {
                int R = m0 + wm + i * 16 + quad * 4 + g;
                out[(size_t)R * 1024 + C] = acc[i][j][g] + bv;
            }
    }
}

// ---------------------------------------------------------------------------
extern "C" void kernel_launch(void* const* d_in, const int* in_sizes, int n_in,
                              void* d_out, int out_size, void* d_ws, size_t ws_size,
                              hipStream_t stream) {
    const float* x    = (const float*)d_in[0];
    const float* Wqkv = (const float*)d_in[1];
    const float* bqkv = (const float*)d_in[2];
    const float* Wo   = (const float*)d_in[3];
    const float* bo   = (const float*)d_in[4];

    char* ws = (char*)d_ws;
    const size_t MB = 1u << 20;
    // Layout (peak 72 MB):
    //   xb    0-16   (dead after gemm_qkv; heads aliases it)
    //   Qb   16-32, Kb 32-48, Vtb 48-64
    //   WqkvT 64-70 (dead after gemm_qkv)
    //   WoT  70-72  (live until gemm_out)
    ushort_t* xb    = (ushort_t*)(ws);
    ushort_t* Qb    = (ushort_t*)(ws + 16 * MB);
    ushort_t* Kb    = (ushort_t*)(ws + 32 * MB);
    ushort_t* Vtb   = (ushort_t*)(ws + 48 * MB);
    ushort_t* WqkvT = (ushort_t*)(ws + 64 * MB);
    ushort_t* WoT   = (ushort_t*)(ws + 70 * MB);
    ushort_t* heads = (ushort_t*)(ws);             // alias xb

    prep<<<8192, 256, 0, stream>>>(x, xb, Wqkv, WqkvT, Wo, WoT);
    gemm_qkv<<<dim3(64, 24), 256, 0, stream>>>(xb, WqkvT, bqkv, Qb, Kb, Vtb);
    attn<<<dim3(8, 16, 8), 256, 0, stream>>>(Qb, Kb, Vtb, heads);
    gemm_out<<<dim3(64, 8), 256, 0, stream>>>(heads, WoT, bo, (float*)d_out);
}

// Round 5
// 229.396 us; speedup vs baseline: 1.1189x; 1.0152x over previous
//
#include <hip/hip_runtime.h>
#include <hip/hip_bf16.h>

typedef unsigned short ushort_t;
typedef __bf16 bf16x8 __attribute__((ext_vector_type(8)));
typedef float floatx4 __attribute__((ext_vector_type(4)));

#define MFMA(a, b, c) __builtin_amdgcn_mfma_f32_16x16x32_bf16(a, b, c, 0, 0, 0)

__device__ __forceinline__ float b2f(ushort_t u) {
    union { ushort_t u; __hip_bfloat16 h; } cvt; cvt.u = u; return __bfloat162float(cvt.h);
}
// HARDWARE bf16 convert: plain fptrunc lowers to v_cvt_pk_bf16_f32 on gfx950
// (RNE, same rounding as the old software __float2bfloat16 path, ~5x fewer VALU ops).
__device__ __forceinline__ ushort_t f2b(float f) {
    union { ushort_t u; __bf16 h; } cvt; cvt.h = (__bf16)f; return cvt.u;
}

// async global->LDS, 16 B/lane. Dest = wave-uniform base + lane*16.
__device__ __forceinline__ void async_copy16(const ushort_t* g, ushort_t* l) {
    __builtin_amdgcn_global_load_lds(
        (const __attribute__((address_space(1))) void*)g,
        (__attribute__((address_space(3))) void*)l, 16, 0, 0);
}

// ---------------------------------------------------------------------------
// Merged preprocessing: one launch, three block-ranges.
//   [0, 4096)        : x fp32 -> bf16 (8 elems/thread)
//   [4096, 7168)     : W_qkv transpose+cvt with QKV column permutation
//   [7168, 8192)     : W_o transpose+cvt
// ---------------------------------------------------------------------------
__global__ void prep(const float* __restrict__ xin, ushort_t* __restrict__ xb,
                     const float* __restrict__ Wqkv, ushort_t* __restrict__ WqkvT,
                     const float* __restrict__ Wo, ushort_t* __restrict__ WoT) {
    __shared__ float tile[32][33];
    int bb = blockIdx.x;
    if (bb < 4096) {
        int i = bb * 256 + threadIdx.x;
        const float4* xf = (const float4*)xin;
        float4 a = xf[i * 2], b = xf[i * 2 + 1];
        union { ushort_t s[8]; uint4 v; } p;
        p.s[0] = f2b(a.x); p.s[1] = f2b(a.y); p.s[2] = f2b(a.z); p.s[3] = f2b(a.w);
        p.s[4] = f2b(b.x); p.s[5] = f2b(b.y); p.s[6] = f2b(b.z); p.s[7] = f2b(b.w);
        ((uint4*)xb)[i] = p.v;
    } else if (bb < 7168) {
        int b2 = bb - 4096;
        int p0 = (b2 % 96) * 32, k0 = (b2 / 96) * 32;
        int which = p0 >> 10, rem = p0 & 1023;
        int n0 = (rem >> 6) * 192 + which * 64 + (rem & 63);
        int tx = threadIdx.x & 31, ty = threadIdx.x >> 5;
#pragma unroll
        for (int i = 0; i < 4; ++i)
            tile[ty + i * 8][tx] = Wqkv[(size_t)(k0 + ty + i * 8) * 3072 + n0 + tx];
        __syncthreads();
#pragma unroll
        for (int i = 0; i < 4; ++i)
            WqkvT[(size_t)(p0 + ty + i * 8) * 1024 + k0 + tx] = f2b(tile[tx][ty + i * 8]);
    } else {
        int b3 = bb - 7168;
        int n0 = (b3 & 31) * 32, k0 = (b3 >> 5) * 32;
        int tx = threadIdx.x & 31, ty = threadIdx.x >> 5;
#pragma unroll
        for (int i = 0; i < 4; ++i)
            tile[ty + i * 8][tx] = Wo[(size_t)(k0 + ty + i * 8) * 1024 + n0 + tx];
        __syncthreads();
#pragma unroll
        for (int i = 0; i < 4; ++i)
            WoT[(size_t)(n0 + ty + i * 8) * 1024 + k0 + tx] = f2b(tile[tx][ty + i * 8]);
    }
}

// swizzled index into the 128x128 transpose buffer
__device__ __forceinline__ int tswz(int n, int m) {
    return n * 128 + (((m >> 3) ^ (n & 15)) << 3) + (m & 7);
}

// ---------------------------------------------------------------------------
// GEMM1: qkv = x @ Wqkv_perm + b.  Q is PRE-SCALED by 0.125*log2(e).
// NATURAL block order (m fastest): all XCDs share one B-panel at a time
// (L2-replicated, 256 KB), A working set per time-slice = 2 MB/XCD, A
// re-reads across n-panels absorbed by L3.  (XCD-chunked swizzle measured
// WORSE: each XCD streamed full 16 MB A per panel, FETCH 44->181 MB.)
// ---------------------------------------------------------------------------
__global__ __launch_bounds__(256, 4) void gemm_qkv(
    const ushort_t* __restrict__ A,
    const ushort_t* __restrict__ Bt,
    const float* __restrict__ bias,
    ushort_t* __restrict__ Qb, ushort_t* __restrict__ Kb, ushort_t* __restrict__ Vtb) {
    const int K = 1024;
    __shared__ __align__(16) ushort_t SH[16384];
    ushort_t* Alds = SH;
    ushort_t* Blds = SH + 8192;
    int tid = threadIdx.x;
    int wave = tid >> 6, lane = tid & 63;
    int quad = lane >> 4, l16 = lane & 15;
    int wm = (wave >> 1) * 64, wn = (wave & 1) * 64;
    int m0 = blockIdx.x * 128, n0 = blockIdx.y * 128;

    floatx4 acc[4][4] = {};

    int srow[4], scol[4];
#pragma unroll
    for (int p = 0; p < 4; ++p) {
        int slot = (wave * 4 + p) * 64 + lane;
        int row = slot >> 3;
        srow[p] = row;
        scol[p] = ((slot & 7) ^ (row & 7)) * 8;
    }

    for (int kt = 0; kt < 16; ++kt) {
        int k0 = kt * 64;
        __syncthreads();
#pragma unroll
        for (int p = 0; p < 4; ++p) {
            int t = wave * 4 + p;
            async_copy16(&A[(m0 + srow[p]) * K + k0 + scol[p]], &Alds[t * 512]);
            async_copy16(&Bt[(n0 + srow[p]) * K + k0 + scol[p]], &Blds[t * 512]);
        }
        __syncthreads();
#pragma unroll
        for (int ki = 0; ki < 2; ++ki) {
            bf16x8 af[4], bfv[4];
            int sc = ((ki * 4 + quad) ^ (l16 & 7)) * 8;
#pragma unroll
            for (int i = 0; i < 4; ++i) {
                __builtin_memcpy(&af[i],  &Alds[(wm + i * 16 + l16) * 64 + sc], 16);
                __builtin_memcpy(&bfv[i], &Blds[(wn + i * 16 + l16) * 64 + sc], 16);
            }
#pragma unroll
            for (int i = 0; i < 4; ++i)
#pragma unroll
                for (int j = 0; j < 4; ++j)
                    acc[i][j] = MFMA(af[i], bfv[j], acc[i][j]);
        }
    }

    int which = n0 >> 10;              // 0=Q, 1=K, 2=V
    int b = m0 >> 10;

    if (which < 2) {
        ushort_t* dst = which ? Kb : Qb;
        float sc = which ? 1.0f : 0.18033688f;   // Q pre-scale: 0.125*log2(e)
#pragma unroll
        for (int j = 0; j < 4; ++j) {
            int C = n0 + wn + j * 16 + l16;
            int c = C & 1023;
            int h = c >> 6, d = c & 63;
            float bv = bias[((C >> 6) & 15) * 192 + which * 64 + (C & 63)];
            size_t hb = (size_t)(b * 16 + h) * 65536 + d;
#pragma unroll
            for (int i = 0; i < 4; ++i)
#pragma unroll
                for (int g = 0; g < 4; ++g) {
                    int n_tok = (m0 & 1023) + wm + i * 16 + quad * 4 + g;
                    dst[hb + (size_t)n_tok * 64] = f2b((acc[i][j][g] + bv) * sc);
                }
        }
    } else {
        __syncthreads();
#pragma unroll
        for (int j = 0; j < 4; ++j) {
            int C = n0 + wn + j * 16 + l16;
            int nl2 = wn + j * 16 + l16;
            float bv = bias[((C >> 6) & 15) * 192 + 128 + (C & 63)];
#pragma unroll
            for (int i = 0; i < 4; ++i)
#pragma unroll
                for (int g = 0; g < 4; ++g) {
                    int ml = wm + i * 16 + quad * 4 + g;
                    SH[tswz(nl2, ml)] = f2b(acc[i][j][g] + bv);
                }
        }
        __syncthreads();
        int r = tid >> 1, half = tid & 1;
        int vcol = (n0 - 2048) + r;
        int h = vcol >> 6, d = vcol & 63;
        size_t base = ((size_t)(b * 16 + h) * 64 + d) * 1024 + (m0 & 1023) + half * 64;
#pragma unroll
        for (int i8 = 0; i8 < 8; ++i8) {
            int chunk = half * 8 + i8;
            uint4 v;
            __builtin_memcpy(&v, &SH[r * 128 + ((chunk ^ (r & 15)) << 3)], 16);
            __builtin_memcpy(&Vtb[base + i8 * 8], &v, 16);
        }
    }
}

// ---------------------------------------------------------------------------
// Flash attention v8: one 128-row q-tile per block, single-buffered K/V,
// Plds now PAD-FREE [128][64] with XOR swizzle (col ^= (row&7)<<3):
// b64 writes land 4 words/bank, b128 reads 8 words/bank -- both uniform
// (throughput minimum, no conflicts).  LDS = 32768 B exactly.
// XCD remap keeps each XCD's K/V working set at 4 MB = its L2.
// Q pre-scaled -> P = exp2(S) directly; f2b is hardware cvt now.
// ---------------------------------------------------------------------------
__global__ __launch_bounds__(256, 4) void attn(
    const ushort_t* __restrict__ Qb, const ushort_t* __restrict__ Kb,
    const ushort_t* __restrict__ Vtb, ushort_t* __restrict__ heads) {
    __shared__ __align__(16) ushort_t Klds[4096];       // swizzled, row = key
    __shared__ __align__(16) ushort_t Vlds[4096];       // swizzled, row = d
    __shared__ __align__(16) ushort_t Plds[128 * 64];   // [q-row][key^swz]
    int tid = threadIdx.x;
    int wave = tid >> 6, lane = tid & 63;
    int quad = lane >> 4, l16 = lane & 15;

    // XCD-aware remap: slot within this XCD iterates q-tiles fastest.
    int slot = blockIdx.y + 16 * blockIdx.z;        // [0,128) per XCD
    int bh = blockIdx.x + 8 * (slot >> 3);          // [0,128), bh%8 == XCD
    int qx = slot & 7;                              // q-tile index [0,8)
    int b = bh >> 4, h = bh & 15;
    const ushort_t* Qh = Qb + (size_t)bh * 65536;
    const ushort_t* Kh = Kb + (size_t)bh * 65536;
    const ushort_t* Vh = Vtb + (size_t)bh * 65536;

    bf16x8 qa[2][2];                   // [mi][ki], B-fragment role
#pragma unroll
    for (int mi = 0; mi < 2; ++mi) {
        int qrow = qx * 128 + wave * 32 + mi * 16 + l16;
        __builtin_memcpy(&qa[mi][0], &Qh[qrow * 64 + quad * 8], 16);
        __builtin_memcpy(&qa[mi][1], &Qh[qrow * 64 + 32 + quad * 8], 16);
    }

    floatx4 oacc[2][4] = {};
    floatx4 oext[2] = {};

    bf16x8 onesfrag;
    {
        ushort_t v = (l16 == 0) ? (ushort_t)0x3F80 : (ushort_t)0;
        ushort_t tmp[8] = {v, v, v, v, v, v, v, v};
        __builtin_memcpy(&onesfrag, tmp, 16);
    }

    int srow[2], scol[2];
#pragma unroll
    for (int p = 0; p < 2; ++p) {
        int slot2 = (wave * 2 + p) * 64 + lane;
        int row = slot2 >> 3;
        srow[p] = row;
        scol[p] = ((slot2 & 7) ^ (row & 7)) * 8;
    }

    // P-row base and swizzle helper (row&7 == l16&7, independent of mi/wave)
    int psw = (l16 & 7) << 3;

    for (int kt = 0; kt < 16; ++kt) {
        int k0 = kt * 64;
        __syncthreads();   // all waves done reading prev tile
#pragma unroll
        for (int p = 0; p < 2; ++p) {
            int t = wave * 2 + p;
            async_copy16(&Kh[(k0 + srow[p]) * 64 + scol[p]], &Klds[t * 512]);
            async_copy16(&Vh[srow[p] * 1024 + k0 + scol[p]], &Vlds[t * 512]);
        }
        __syncthreads();   // staged data visible (vmcnt drained by compiler)

        // ---- St = K Q^T; P = exp2(St) -> Plds (swizzled, pad-free)
        bf16x8 kf[4][2];
#pragma unroll
        for (int n = 0; n < 4; ++n)
#pragma unroll
            for (int ki = 0; ki < 2; ++ki) {
                int sc = ((ki * 4 + quad) ^ (l16 & 7)) * 8;
                __builtin_memcpy(&kf[n][ki], &Klds[(n * 16 + l16) * 64 + sc], 16);
            }
#pragma unroll
        for (int mi = 0; mi < 2; ++mi) {
            int prow = wave * 32 + mi * 16 + l16;
#pragma unroll
            for (int n = 0; n < 4; ++n) {
                floatx4 z = {0.f, 0.f, 0.f, 0.f};
#pragma unroll
                for (int ki = 0; ki < 2; ++ki)
                    z = MFMA(kf[n][ki], qa[mi][ki], z);
                union { ushort_t s[4]; double d8; } pk;
#pragma unroll
                for (int g = 0; g < 4; ++g)
                    pk.s[g] = f2b(__builtin_exp2f(z[g]));
                __builtin_memcpy(
                    &Plds[prow * 64 + ((n * 16 + quad * 4) ^ psw)], &pk, 8);
            }
        }

        // ---- O += P V ; l += P ones  (P read back same-wave, no barrier)
        bf16x8 vf[4][2];
#pragma unroll
        for (int n = 0; n < 4; ++n)
#pragma unroll
            for (int ki = 0; ki < 2; ++ki) {
                int sc = ((ki * 4 + quad) ^ (l16 & 7)) * 8;
                __builtin_memcpy(&vf[n][ki], &Vlds[(n * 16 + l16) * 64 + sc], 16);
            }
#pragma unroll
        for (int mi = 0; mi < 2; ++mi) {
            bf16x8 pa[2];
            int prow = wave * 32 + mi * 16 + l16;
#pragma unroll
            for (int ki = 0; ki < 2; ++ki)
                __builtin_memcpy(&pa[ki],
                    &Plds[prow * 64 + ((ki * 32 + quad * 8) ^ psw)], 16);
            __builtin_amdgcn_s_setprio(1);
#pragma unroll
            for (int n = 0; n < 4; ++n)
#pragma unroll
                for (int ki = 0; ki < 2; ++ki)
                    oacc[mi][n] = MFMA(pa[ki], vf[n][ki], oacc[mi][n]);
#pragma unroll
            for (int ki = 0; ki < 2; ++ki)
                oext[mi] = MFMA(pa[ki], onesfrag, oext[mi]);
            __builtin_amdgcn_s_setprio(0);
        }
    }

    // normalize + write heads (B, N, H*HD) bf16
#pragma unroll
    for (int mi = 0; mi < 2; ++mi)
#pragma unroll
        for (int g = 0; g < 4; ++g) {
            float l = __shfl(oext[mi][g], (lane & 48));
            float inv = 1.f / l;
            int n_tok = qx * 128 + wave * 32 + mi * 16 + quad * 4 + g;
#pragma unroll
            for (int n = 0; n < 4; ++n)
                heads[(size_t)(b * 1024 + n_tok) * 1024 + h * 64 + n * 16 + l16] =
                    f2b(oacc[mi][n][g] * inv);
        }
}

// ---------------------------------------------------------------------------
// GEMM2: out = heads(8192x1024) @ W_o + b_o  -> FP32 d_out.  Natural order.
// ---------------------------------------------------------------------------
__global__ __launch_bounds__(256, 4) void gemm_out(
    const ushort_t* __restrict__ A,
    const ushort_t* __restrict__ Bt,
    const float* __restrict__ bias,
    float* __restrict__ out) {
    const int K = 1024;
    __shared__ __align__(16) ushort_t Alds[128 * 64];
    __shared__ __align__(16) ushort_t Blds[128 * 64];
    int tid = threadIdx.x;
    int wave = tid >> 6, lane = tid & 63;
    int quad = lane >> 4, l16 = lane & 15;
    int wm = (wave >> 1) * 64, wn = (wave & 1) * 64;
    int m0 = blockIdx.x * 128, n0 = blockIdx.y * 128;

    floatx4 acc[4][4] = {};

    int srow[4], scol[4];
#pragma unroll
    for (int p = 0; p < 4; ++p) {
        int slot = (wave * 4 + p) * 64 + lane;
        int row = slot >> 3;
        srow[p] = row;
        scol[p] = ((slot & 7) ^ (row & 7)) * 8;
    }

    for (int kt = 0; kt < 16; ++kt) {
        int k0 = kt * 64;
        __syncthreads();
#pragma unroll
        for (int p = 0; p < 4; ++p) {
            int t = wave * 4 + p;
            async_copy16(&A[(m0 + srow[p]) * K + k0 + scol[p]], &Alds[t * 512]);
            async_copy16(&Bt[(n0 + srow[p]) * K + k0 + scol[p]], &Blds[t * 512]);
        }
        __syncthreads();
#pragma unroll
        for (int ki = 0; ki < 2; ++ki) {
            bf16x8 af[4], bfv[4];
            int sc = ((ki * 4 + quad) ^ (l16 & 7)) * 8;
#pragma unroll
            for (int i = 0; i < 4; ++i) {
                __builtin_memcpy(&af[i],  &Alds[(wm + i * 16 + l16) * 64 + sc], 16);
                __builtin_memcpy(&bfv[i], &Blds[(wn + i * 16 + l16) * 64 + sc], 16);
            }
#pragma unroll
            for (int i = 0; i < 4; ++i)
#pragma unroll
                for (int j = 0; j < 4; ++j)
                    acc[i][j] = MFMA(af[i], bfv[j], acc[i][j]);
        }
    }

#pragma unroll
    for (int j = 0; j < 4; ++j) {
        int C = n0 + wn + j * 16 + l16;
        float bv = bias[C];
#pragma unroll
        for (int i = 0; i < 4; ++i)
#pragma unroll
            for (int g = 0; g < 4; ++g) {
                int R = m0 + wm + i * 16 + quad * 4 + g;
                out[(size_t)R * 1024 + C] = acc[i][j][g] + bv;
            }
    }
}

// ---------------------------------------------------------------------------
extern "C" void kernel_launch(void* const* d_in, const int* in_sizes, int n_in,
                              void* d_out, int out_size, void* d_ws, size_t ws_size,
                              hipStream_t stream) {
    const float* x    = (const float*)d_in[0];
    const float* Wqkv = (const float*)d_in[1];
    const float* bqkv = (const float*)d_in[2];
    const float* Wo   = (const float*)d_in[3];
    const float* bo   = (const float*)d_in[4];

    char* ws = (char*)d_ws;
    const size_t MB = 1u << 20;
    // Layout (peak 72 MB):
    //   xb    0-16   (dead after gemm_qkv; heads aliases it)
    //   Qb   16-32, Kb 32-48, Vtb 48-64
    //   WqkvT 64-70 (dead after gemm_qkv)
    //   WoT  70-72  (live until gemm_out)
    ushort_t* xb    = (ushort_t*)(ws);
    ushort_t* Qb    = (ushort_t*)(ws + 16 * MB);
    ushort_t* Kb    = (ushort_t*)(ws + 32 * MB);
    ushort_t* Vtb   = (ushort_t*)(ws + 48 * MB);
    ushort_t* WqkvT = (ushort_t*)(ws + 64 * MB);
    ushort_t* WoT   = (ushort_t*)(ws + 70 * MB);
    ushort_t* heads = (ushort_t*)(ws);             // alias xb

    prep<<<8192, 256, 0, stream>>>(x, xb, Wqkv, WqkvT, Wo, WoT);
    gemm_qkv<<<dim3(64, 24), 256, 0, stream>>>(xb, WqkvT, bqkv, Qb, Kb, Vtb);
    attn<<<dim3(8, 16, 8), 256, 0, stream>>>(Qb, Kb, Vtb, heads);
    gemm_out<<<dim3(64, 8), 256, 0, stream>>>(heads, WoT, bo, (float*)d_out);
}